// Round 1
// baseline (228.953 us; speedup 1.0000x reference)
//
#include <hip/hip_runtime.h>
#include <math.h>

#define NN 1000000
#define F 128
#define N0 16384
#define N1 4096

// ---------------- map kernels (last-occurrence-wins scatter emulation) -------

__global__ void k_init_maps(int* __restrict__ maps, int n4) {
    int i = blockIdx.x * blockDim.x + threadIdx.x;
    if (i < n4) ((int4*)maps)[i] = make_int4(-1, -1, -1, -1);
}

__global__ void k_build_map(const int* __restrict__ ns, int n, int* __restrict__ map) {
    int i = blockIdx.x * blockDim.x + threadIdx.x;
    if (i < n) atomicMax(&map[ns[i]], i);
}

// ---------------- q-GEMM + weighted aggregation ------------------------------
// rows m = node*16 + t over the whole layer; A[m,:] = resolved h row of nb[m]
// agg[node][j] = sum_t w[t]*leaky(QK dot + Qb[j]) / sum_t w[t]

__global__ __launch_bounds__(256, 2) void k_qagg(
    const float* __restrict__ h, const float* __restrict__ newprev,
    const int* __restrict__ mapprev,
    const int* __restrict__ nb, const float* __restrict__ nbw,
    const float* __restrict__ Qw, const float* __restrict__ Qb,
    float* __restrict__ agg)
{
    __shared__ float As[64][128];   // [k][m]
    __shared__ float Bs[64][128];   // [k][j]
    const int tid = threadIdx.x;
    const int mbase = blockIdx.x * 128;
    const int ty = tid >> 4, tx = tid & 15;
    const int mloc = tid >> 1;
    const int khalf = (tid & 1) * 32;

    // resolve gathered source row (constant across k-chunks)
    int g = nb[mbase + mloc];
    const float* src = h + (size_t)g * F;
    if (mapprev) {
        int p = mapprev[g];
        if (p >= 0) src = newprev + (size_t)p * F;
    }
    const int j = tid >> 1;

    float acc[8][8];
#pragma unroll
    for (int r = 0; r < 8; ++r)
#pragma unroll
        for (int c = 0; c < 8; ++c) acc[r][c] = 0.f;

    for (int kc = 0; kc < 2; ++kc) {
        {   // stage A (transposed)
            const float4* s4 = (const float4*)(src + kc * 64 + khalf);
#pragma unroll
            for (int c = 0; c < 8; ++c) {
                float4 v = s4[c];
                int kk = khalf + c * 4;
                As[kk + 0][mloc] = v.x; As[kk + 1][mloc] = v.y;
                As[kk + 2][mloc] = v.z; As[kk + 3][mloc] = v.w;
            }
        }
        {   // stage B = Qw^T chunk
            const float4* s4 = (const float4*)(Qw + (size_t)j * F + kc * 64 + khalf);
#pragma unroll
            for (int c = 0; c < 8; ++c) {
                float4 v = s4[c];
                int kk = khalf + c * 4;
                Bs[kk + 0][j] = v.x; Bs[kk + 1][j] = v.y;
                Bs[kk + 2][j] = v.z; Bs[kk + 3][j] = v.w;
            }
        }
        __syncthreads();
#pragma unroll 2
        for (int k = 0; k < 64; ++k) {
            float a[8], b[8];
            *(float4*)&a[0] = *(const float4*)&As[k][ty * 8];
            *(float4*)&a[4] = *(const float4*)&As[k][ty * 8 + 4];
            *(float4*)&b[0] = *(const float4*)&Bs[k][tx * 8];
            *(float4*)&b[4] = *(const float4*)&Bs[k][tx * 8 + 4];
#pragma unroll
            for (int r = 0; r < 8; ++r)
#pragma unroll
                for (int c = 0; c < 8; ++c)
                    acc[r][c] = fmaf(a[r], b[c], acc[r][c]);
        }
        __syncthreads();
    }

    // epilogue: bias + leaky + weighted partial sum over this thread's 8 rows
    const int nodeg = (mbase >> 4) + (ty >> 1);
    float qb[8];
#pragma unroll
    for (int c = 0; c < 8; ++c) qb[c] = Qb[tx * 8 + c];
    float part[8];
#pragma unroll
    for (int c = 0; c < 8; ++c) part[c] = 0.f;
#pragma unroll
    for (int r = 0; r < 8; ++r) {
        int t = (ty & 1) * 8 + r;
        float w = nbw[nodeg * 16 + t];
#pragma unroll
        for (int c = 0; c < 8; ++c) {
            float v = acc[r][c] + qb[c];
            v = v > 0.f ? v : 0.01f * v;
            part[c] = fmaf(w, v, part[c]);
        }
    }
    float* pl = &As[0][0];   // 16x128 scratch (reuse As)
#pragma unroll
    for (int c = 0; c < 8; ++c) pl[ty * 128 + tx * 8 + c] = part[c];
    __syncthreads();
    if (ty < 8) {
        int ng = (mbase >> 4) + ty;
        float wsum = 0.f;
#pragma unroll
        for (int t = 0; t < 16; ++t) wsum += nbw[ng * 16 + t];
        float inv = (wsum == 0.f) ? 1.f : 1.f / wsum;
#pragma unroll
        for (int c = 0; c < 8; ++c) {
            float v = pl[(2 * ty) * 128 + tx * 8 + c] + pl[(2 * ty + 1) * 128 + tx * 8 + c];
            agg[(size_t)ng * F + tx * 8 + c] = v * inv;
        }
    }
}

// ---------------- dense GEMM: leaky(cat(self, agg) @ Ww^T + Wb), normalize ---

__global__ __launch_bounds__(256, 2) void k_dense(
    const float* __restrict__ h, const float* __restrict__ newprev,
    const int* __restrict__ mapprev,
    const int* __restrict__ nodeset, const float* __restrict__ agg,
    const float* __restrict__ Ww, const float* __restrict__ Wb,
    float* __restrict__ outnew)
{
    __shared__ float As[64][128];
    __shared__ float Bs[64][128];
    __shared__ float rnorm[128];
    const int tid = threadIdx.x;
    const int mbase = blockIdx.x * 128;
    const int ty = tid >> 4, tx = tid & 15;
    const int mloc = tid >> 1;
    const int khalf = (tid & 1) * 32;

    int gself = nodeset[mbase + mloc];
    const float* selfsrc = h + (size_t)gself * F;
    if (mapprev) {
        int p = mapprev[gself];
        if (p >= 0) selfsrc = newprev + (size_t)p * F;
    }
    const float* aggsrc = agg + (size_t)(mbase + mloc) * F;
    const int j = tid >> 1;

    float acc[8][8];
#pragma unroll
    for (int r = 0; r < 8; ++r)
#pragma unroll
        for (int c = 0; c < 8; ++c) acc[r][c] = 0.f;

    for (int kc = 0; kc < 4; ++kc) {
        const float* srow = (kc < 2) ? (selfsrc + kc * 64) : (aggsrc + (kc - 2) * 64);
        {
            const float4* s4 = (const float4*)(srow + khalf);
#pragma unroll
            for (int c = 0; c < 8; ++c) {
                float4 v = s4[c];
                int kk = khalf + c * 4;
                As[kk + 0][mloc] = v.x; As[kk + 1][mloc] = v.y;
                As[kk + 2][mloc] = v.z; As[kk + 3][mloc] = v.w;
            }
        }
        {
            const float4* s4 = (const float4*)(Ww + (size_t)j * 256 + kc * 64 + khalf);
#pragma unroll
            for (int c = 0; c < 8; ++c) {
                float4 v = s4[c];
                int kk = khalf + c * 4;
                Bs[kk + 0][j] = v.x; Bs[kk + 1][j] = v.y;
                Bs[kk + 2][j] = v.z; Bs[kk + 3][j] = v.w;
            }
        }
        __syncthreads();
#pragma unroll 2
        for (int k = 0; k < 64; ++k) {
            float a[8], b[8];
            *(float4*)&a[0] = *(const float4*)&As[k][ty * 8];
            *(float4*)&a[4] = *(const float4*)&As[k][ty * 8 + 4];
            *(float4*)&b[0] = *(const float4*)&Bs[k][tx * 8];
            *(float4*)&b[4] = *(const float4*)&Bs[k][tx * 8 + 4];
#pragma unroll
            for (int r = 0; r < 8; ++r)
#pragma unroll
                for (int c = 0; c < 8; ++c)
                    acc[r][c] = fmaf(a[r], b[c], acc[r][c]);
        }
        __syncthreads();
    }

    // epilogue: bias + leaky, then row L2-normalize
    float wb[8];
#pragma unroll
    for (int c = 0; c < 8; ++c) wb[c] = Wb[tx * 8 + c];
    float ss[8];
#pragma unroll
    for (int r = 0; r < 8; ++r) {
        ss[r] = 0.f;
#pragma unroll
        for (int c = 0; c < 8; ++c) {
            float v = acc[r][c] + wb[c];
            v = v > 0.f ? v : 0.01f * v;
            acc[r][c] = v;
            ss[r] = fmaf(v, v, ss[r]);
        }
    }
    float* rs = &As[0][0];   // [128][16] scratch
#pragma unroll
    for (int r = 0; r < 8; ++r) rs[(ty * 8 + r) * 16 + tx] = ss[r];
    __syncthreads();
    if (tid < 128) {
        float s = 0.f;
#pragma unroll
        for (int i = 0; i < 16; ++i) s += rs[tid * 16 + i];
        float n = sqrtf(s);
        rnorm[tid] = (n == 0.f) ? 1.f : 1.f / n;
    }
    __syncthreads();
#pragma unroll
    for (int r = 0; r < 8; ++r) {
        float sc = rnorm[ty * 8 + r];
#pragma unroll
        for (int c = 0; c < 8; ++c)
            outnew[(size_t)(mbase + ty * 8 + r) * F + tx * 8 + c] = acc[r][c] * sc;
    }
}

// ---------------- final output gather ---------------------------------------

__global__ void k_out(const float* __restrict__ new1, const int* __restrict__ map1,
                      const int* __restrict__ ns1, float* __restrict__ out, int n) {
    int idx = blockIdx.x * blockDim.x + threadIdx.x;
    if (idx < n * 32) {
        int i = idx >> 5, c = idx & 31;
        int p = map1[ns1[i]];
        ((float4*)out)[(size_t)i * 32 + c] = ((const float4*)(new1 + (size_t)p * F))[c];
    }
}

// ---------------- launcher ---------------------------------------------------

extern "C" void kernel_launch(void* const* d_in, const int* in_sizes, int n_in,
                              void* d_out, int out_size, void* d_ws, size_t ws_size,
                              hipStream_t stream) {
    const float* h    = (const float*)d_in[0];
    const float* Qw0  = (const float*)d_in[1];
    const float* Qb0  = (const float*)d_in[2];
    const float* Ww0  = (const float*)d_in[3];
    const float* Wb0  = (const float*)d_in[4];
    const float* Qw1  = (const float*)d_in[5];
    const float* Qb1  = (const float*)d_in[6];
    const float* Ww1  = (const float*)d_in[7];
    const float* Wb1  = (const float*)d_in[8];
    const int*   ns0  = (const int*)d_in[9];
    const int*   nb0  = (const int*)d_in[10];
    const float* nbw0 = (const float*)d_in[11];
    const int*   ns1  = (const int*)d_in[12];
    const int*   nb1  = (const int*)d_in[13];
    const float* nbw1 = (const float*)d_in[14];

    // workspace layout: map0 (1M int) | map1 (1M int) | new0 | new1 | agg
    int* map0 = (int*)d_ws;
    int* map1 = map0 + NN;
    float* new0 = (float*)(map1 + NN);
    float* new1 = new0 + (size_t)N0 * F;
    float* agg  = new1 + (size_t)N1 * F;

    k_init_maps<<<(2 * NN / 4 + 255) / 256, 256, 0, stream>>>(map0, 2 * NN / 4);
    k_build_map<<<(N0 + 255) / 256, 256, 0, stream>>>(ns0, N0, map0);
    k_build_map<<<(N1 + 255) / 256, 256, 0, stream>>>(ns1, N1, map1);

    // layer 0 (reads original h only)
    k_qagg<<<N0 * 16 / 128, 256, 0, stream>>>(h, nullptr, nullptr, nb0, nbw0, Qw0, Qb0, agg);
    k_dense<<<N0 / 128, 256, 0, stream>>>(h, nullptr, nullptr, ns0, agg, Ww0, Wb0, new0);

    // layer 1 (reads h with nodeset0 rows redirected to new0 via map0)
    k_qagg<<<N1 * 16 / 128, 256, 0, stream>>>(h, new0, map0, nb1, nbw1, Qw1, Qb1, agg);
    k_dense<<<N1 / 128, 256, 0, stream>>>(h, new0, map0, ns1, agg, Ww1, Wb1, new1);

    // out[i] = new1[last position of ns1[i] in ns1]
    k_out<<<(N1 * 32 + 255) / 256, 256, 0, stream>>>(new1, map1, ns1, (float*)d_out, N1);
}

// Round 2
// 100.945 us; speedup vs baseline: 2.2681x; 2.2681x over previous
//
#include <hip/hip_runtime.h>
#include <math.h>

#define NN 1000000
#define F 128
#define N0 16384
#define N1 4096

typedef __attribute__((ext_vector_type(8))) short bf16x8;
typedef __attribute__((ext_vector_type(4))) float f32x4;

__device__ inline unsigned short f2b(float f) {
    union { float f; unsigned u; } v; v.f = f;
    unsigned r = v.u + 0x7FFFu + ((v.u >> 16) & 1u);
    return (unsigned short)(r >> 16);
}

__device__ inline bf16x8 pack8(float4 a, float4 b) {
    bf16x8 r;
    r[0] = (short)f2b(a.x); r[1] = (short)f2b(a.y);
    r[2] = (short)f2b(a.z); r[3] = (short)f2b(a.w);
    r[4] = (short)f2b(b.x); r[5] = (short)f2b(b.y);
    r[6] = (short)f2b(b.z); r[7] = (short)f2b(b.w);
    return r;
}

// ---------------- map kernels (last-occurrence-wins scatter emulation) -------

__global__ void k_init_maps(int* __restrict__ maps, int n4) {
    int i = blockIdx.x * blockDim.x + threadIdx.x;
    if (i < n4) ((int4*)maps)[i] = make_int4(-1, -1, -1, -1);
}

__global__ void k_build_map(const int* __restrict__ ns, int n, int* __restrict__ map) {
    int i = blockIdx.x * blockDim.x + threadIdx.x;
    if (i < n) atomicMax(&map[ns[i]], i);
}

// ---------------- fp32 -> bf16 weight conversion -----------------------------

__global__ void k_cvt(const float* __restrict__ a, unsigned short* __restrict__ b, int n) {
    int i = blockIdx.x * blockDim.x + threadIdx.x;
    if (i < n) b[i] = f2b(a[i]);
}

// ---------------- q-GEMM + weighted aggregation (MFMA) -----------------------
// wave handles 2 nodes; node's 16 neighbors = 16-row M-tile; K=128, Ncols=128.

__global__ __launch_bounds__(256) void k_qagg(
    const float* __restrict__ h, const float* __restrict__ newprev,
    const int* __restrict__ mapprev,
    const int* __restrict__ nb, const float* __restrict__ nbw,
    const unsigned short* __restrict__ Qwb, const float* __restrict__ Qb,
    unsigned short* __restrict__ aggb)
{
    __shared__ unsigned short lQ[128 * 128];   // 32 KB, XOR-swizzled rows
    const int tid = threadIdx.x;

    // stage Qw (bf16, row-major [j][k]) into LDS, swizzle byte ^= (j&7)<<4
    for (int c = tid; c < 2048; c += 256) {           // 16B chunks
        int j = c >> 4;
        uint4 v = ((const uint4*)Qwb)[c];
        int byte = (c << 4) ^ ((j & 7) << 4);
        *(uint4*)((char*)lQ + byte) = v;
    }
    __syncthreads();

    const int wid = tid >> 6, lane = tid & 63;
    const int row = lane & 15, kg = lane >> 4;
    const long nodebase = (long)blockIdx.x * 8 + wid * 2;

    // gather + convert A fragments for both nodes (whole row held in regs)
    bf16x8 A[2][4];
#pragma unroll
    for (int nn = 0; nn < 2; ++nn) {
        long node = nodebase + nn;
        int g = nb[node * 16 + row];
        const float* src = h + (size_t)g * F;
        if (mapprev) {
            int p = mapprev[g];
            if (p >= 0) src = newprev + (size_t)p * F;
        }
        const float4* s4 = (const float4*)src;
#pragma unroll
        for (int kk = 0; kk < 4; ++kk) {
            float4 v0 = s4[kk * 8 + kg * 2];
            float4 v1 = s4[kk * 8 + kg * 2 + 1];
            A[nn][kk] = pack8(v0, v1);
        }
    }

    f32x4 acc[2][8];
#pragma unroll
    for (int nn = 0; nn < 2; ++nn)
#pragma unroll
        for (int jt = 0; jt < 8; ++jt)
            acc[nn][jt] = (f32x4){0.f, 0.f, 0.f, 0.f};

#pragma unroll
    for (int kk = 0; kk < 4; ++kk) {
        bf16x8 Bf[8];
#pragma unroll
        for (int jt = 0; jt < 8; ++jt) {
            int j = jt * 16 + row;
            int byte = ((j << 8) + (kk << 6) + (kg << 4)) ^ ((j & 7) << 4);
            Bf[jt] = *(bf16x8*)((char*)lQ + byte);
        }
#pragma unroll
        for (int jt = 0; jt < 8; ++jt) {
            acc[0][jt] = __builtin_amdgcn_mfma_f32_16x16x32_bf16(A[0][kk], Bf[jt], acc[0][jt], 0, 0, 0);
            acc[1][jt] = __builtin_amdgcn_mfma_f32_16x16x32_bf16(A[1][kk], Bf[jt], acc[1][jt], 0, 0, 0);
        }
    }

    // epilogue: bias + leaky + weighted row-reduction, safediv, bf16 store
#pragma unroll
    for (int nn = 0; nn < 2; ++nn) {
        long node = nodebase + nn;
        float w[4];
#pragma unroll
        for (int r = 0; r < 4; ++r) w[r] = nbw[node * 16 + kg * 4 + r];
        float ws = w[0] + w[1] + w[2] + w[3];
        ws += __shfl_xor(ws, 16);
        ws += __shfl_xor(ws, 32);
        float inv = (ws == 0.f) ? 1.f : 1.f / ws;
#pragma unroll
        for (int jt = 0; jt < 8; ++jt) {
            float qb = Qb[jt * 16 + row];
            float t = 0.f;
#pragma unroll
            for (int r = 0; r < 4; ++r) {
                float v = acc[nn][jt][r] + qb;
                v = v > 0.f ? v : 0.01f * v;
                t = fmaf(w[r], v, t);
            }
            t += __shfl_xor(t, 16);
            t += __shfl_xor(t, 32);
            if (lane < 16) aggb[node * 128 + jt * 16 + lane] = f2b(t * inv);
        }
    }
}

// ---------------- dense GEMM: leaky(cat(self, agg) @ Ww^T + Wb), normalize ---
// wave = 16 nodes (one M-tile), K=256 (self 128 | agg 128), Ncols=128.

__global__ __launch_bounds__(256) void k_dense(
    const float* __restrict__ h, const float* __restrict__ newprev,
    const int* __restrict__ mapprev,
    const int* __restrict__ nodeset, const unsigned short* __restrict__ aggb,
    const unsigned short* __restrict__ Wwb, const float* __restrict__ Wb,
    float* __restrict__ outnew)
{
    __shared__ unsigned short lW[128 * 256];   // 64 KB, XOR-swizzled rows
    const int tid = threadIdx.x;

    for (int c = tid; c < 4096; c += 256) {
        int j = c >> 5;
        uint4 v = ((const uint4*)Wwb)[c];
        int byte = (c << 4) ^ ((j & 7) << 4);
        *(uint4*)((char*)lW + byte) = v;
    }
    __syncthreads();

    const int wid = tid >> 6, lane = tid & 63;
    const int row = lane & 15, kg = lane >> 4;
    const long mbase = (long)blockIdx.x * 64 + wid * 16;
    const long m = mbase + row;

    int gs = nodeset[m];
    const float* src = h + (size_t)gs * F;
    if (mapprev) {
        int p = mapprev[gs];
        if (p >= 0) src = newprev + (size_t)p * F;
    }

    bf16x8 A[8];
    const float4* s4 = (const float4*)src;
#pragma unroll
    for (int kk = 0; kk < 4; ++kk) {
        float4 v0 = s4[kk * 8 + kg * 2];
        float4 v1 = s4[kk * 8 + kg * 2 + 1];
        A[kk] = pack8(v0, v1);
    }
    const bf16x8* a4 = (const bf16x8*)(aggb + m * 128);
#pragma unroll
    for (int kk = 0; kk < 4; ++kk) A[4 + kk] = a4[kk * 4 + kg];

    f32x4 acc[8];
#pragma unroll
    for (int jt = 0; jt < 8; ++jt) acc[jt] = (f32x4){0.f, 0.f, 0.f, 0.f};

#pragma unroll
    for (int kk = 0; kk < 8; ++kk) {
        bf16x8 Bf[8];
#pragma unroll
        for (int jt = 0; jt < 8; ++jt) {
            int j = jt * 16 + row;
            int byte = ((j << 9) + (kk << 6) + (kg << 4)) ^ ((j & 7) << 4);
            Bf[jt] = *(bf16x8*)((char*)lW + byte);
        }
#pragma unroll
        for (int jt = 0; jt < 8; ++jt)
            acc[jt] = __builtin_amdgcn_mfma_f32_16x16x32_bf16(A[kk], Bf[jt], acc[jt], 0, 0, 0);
    }

    // epilogue: bias + leaky, row sum-of-squares, normalize, store
    float ss[4] = {0.f, 0.f, 0.f, 0.f};
#pragma unroll
    for (int jt = 0; jt < 8; ++jt) {
        float wb = Wb[jt * 16 + row];
#pragma unroll
        for (int r = 0; r < 4; ++r) {
            float v = acc[jt][r] + wb;
            v = v > 0.f ? v : 0.01f * v;
            acc[jt][r] = v;
            ss[r] = fmaf(v, v, ss[r]);
        }
    }
#pragma unroll
    for (int r = 0; r < 4; ++r) {
        ss[r] += __shfl_xor(ss[r], 1);
        ss[r] += __shfl_xor(ss[r], 2);
        ss[r] += __shfl_xor(ss[r], 4);
        ss[r] += __shfl_xor(ss[r], 8);
    }
    float invn[4];
#pragma unroll
    for (int r = 0; r < 4; ++r) {
        float n = sqrtf(ss[r]);
        invn[r] = (n == 0.f) ? 1.f : 1.f / n;
    }
#pragma unroll
    for (int jt = 0; jt < 8; ++jt)
#pragma unroll
        for (int r = 0; r < 4; ++r)
            outnew[(size_t)(mbase + kg * 4 + r) * F + jt * 16 + row] = acc[jt][r] * invn[r];
}

// ---------------- final output gather ---------------------------------------

__global__ void k_out(const float* __restrict__ new1, const int* __restrict__ map1,
                      const int* __restrict__ ns1, float* __restrict__ out, int n) {
    int idx = blockIdx.x * blockDim.x + threadIdx.x;
    if (idx < n * 32) {
        int i = idx >> 5, c = idx & 31;
        int p = map1[ns1[i]];
        ((float4*)out)[(size_t)i * 32 + c] = ((const float4*)(new1 + (size_t)p * F))[c];
    }
}

// ---------------- launcher ---------------------------------------------------

extern "C" void kernel_launch(void* const* d_in, const int* in_sizes, int n_in,
                              void* d_out, int out_size, void* d_ws, size_t ws_size,
                              hipStream_t stream) {
    const float* h    = (const float*)d_in[0];
    const float* Qw0  = (const float*)d_in[1];
    const float* Qb0  = (const float*)d_in[2];
    const float* Ww0  = (const float*)d_in[3];
    const float* Wb0  = (const float*)d_in[4];
    const float* Qw1  = (const float*)d_in[5];
    const float* Qb1  = (const float*)d_in[6];
    const float* Ww1  = (const float*)d_in[7];
    const float* Wb1  = (const float*)d_in[8];
    const int*   ns0  = (const int*)d_in[9];
    const int*   nb0  = (const int*)d_in[10];
    const float* nbw0 = (const float*)d_in[11];
    const int*   ns1  = (const int*)d_in[12];
    const int*   nb1  = (const int*)d_in[13];
    const float* nbw1 = (const float*)d_in[14];

    // ws: map0 | map1 | new0 f32 | new1 f32 | aggb bf16 | Qw0b | Qw1b | Ww0b | Ww1b
    int* map0 = (int*)d_ws;
    int* map1 = map0 + NN;
    float* new0 = (float*)(map1 + NN);
    float* new1 = new0 + (size_t)N0 * F;
    unsigned short* aggb = (unsigned short*)(new1 + (size_t)N1 * F);
    unsigned short* Qw0b = aggb + (size_t)N0 * F;
    unsigned short* Qw1b = Qw0b + 128 * 128;
    unsigned short* Ww0b = Qw1b + 128 * 128;
    unsigned short* Ww1b = Ww0b + 128 * 256;

    k_init_maps<<<(2 * NN / 4 + 255) / 256, 256, 0, stream>>>(map0, 2 * NN / 4);
    k_build_map<<<(N0 + 255) / 256, 256, 0, stream>>>(ns0, N0, map0);
    k_build_map<<<(N1 + 255) / 256, 256, 0, stream>>>(ns1, N1, map1);
    k_cvt<<<64, 256, 0, stream>>>(Qw0, Qw0b, 128 * 128);
    k_cvt<<<64, 256, 0, stream>>>(Qw1, Qw1b, 128 * 128);
    k_cvt<<<128, 256, 0, stream>>>(Ww0, Ww0b, 128 * 256);
    k_cvt<<<128, 256, 0, stream>>>(Ww1, Ww1b, 128 * 256);

    // layer 0
    k_qagg<<<N0 / 8, 256, 0, stream>>>(h, nullptr, nullptr, nb0, nbw0, Qw0b, Qb0, aggb);
    k_dense<<<N0 / 64, 256, 0, stream>>>(h, nullptr, nullptr, ns0, aggb, Ww0b, Wb0, new0);

    // layer 1 (h with nodeset0 rows redirected to new0 via map0)
    k_qagg<<<N1 / 8, 256, 0, stream>>>(h, new0, map0, nb1, nbw1, Qw1b, Qb1, aggb);
    k_dense<<<N1 / 64, 256, 0, stream>>>(h, new0, map0, ns1, aggb, Ww1b, Wb1, new1);

    k_out<<<(N1 * 32 + 255) / 256, 256, 0, stream>>>(new1, map1, ns1, (float*)d_out, N1);
}